// Round 7
// baseline (225.884 us; speedup 1.0000x reference)
//
#include <hip/hip_runtime.h>

typedef _Float16 hf;
typedef _Float16 half2v __attribute__((ext_vector_type(2)));
typedef _Float16 half8 __attribute__((ext_vector_type(8)));
typedef float f32x4 __attribute__((ext_vector_type(4)));
typedef int int4v __attribute__((ext_vector_type(4)));

constexpr int Steps = 27;

// ws half-index layout:
//   wrec : [0, 393216)          (((cls*8+wv)*6+gate)*8+ks)*512 + lane*8 + j   K=[0,256)
//   wx   : [393216, 589824)     (((cls*6+gate)*8+wv)*4+ks)*512 + lane*8 + j   K=[256,384)
//   fc3  : [589824, 598016)     (wv*2+ks)*512 + lane*8 + j
//   fc4  : [598016, 614400)     (wv*4+ks)*512 + lane*8 + j
//   xWb  : [614400, +18874368)  [cls][bn][cell][d*6+gate] fp16
constexpr int OFF_WX = 393216;
constexpr int OFF_F3 = 589824;
constexpr int OFF_F4 = 598016;
constexpr int OFF_XW = 614400;

__device__ __forceinline__ int aidx(int r, int k) {  // halfs, K=256 (witran A)
  int blk = k >> 3;
  return r * 256 + (((blk ^ (r & 7)) & 31) << 3) + (k & 7);
}
__device__ __forceinline__ int hidx(int r, int k) {  // halfs, K=128 (prelude h buffers)
  int blk = k >> 3;
  return r * 128 + (((blk ^ (r & 15)) & 15) << 3) + (k & 7);
}
__device__ __forceinline__ int xidx(int r, int k) {  // halfs, K=64 (prelude x)
  int blk = k >> 3;
  return r * 64 + (((blk ^ (r & 7)) & 7) << 3) + (k & 7);
}
__device__ __forceinline__ float sigmoidf_(float x) { return 1.0f / (1.0f + __expf(-x)); }
__device__ __forceinline__ float tanh_(float x) { return 1.0f - 2.0f / (__expf(2.0f * x) + 1.0f); }

// ---- kernel 1: all weights -> fragment-ordered fp16 (coalesced writes) ----
__global__ __launch_bounds__(512) void prep(const float* __restrict__ fc3_w,
                                            const float* __restrict__ fc4_w,
                                            const float* __restrict__ W_enc,
                                            hf* __restrict__ wsh) {
  int idx = blockIdx.x * 512 + threadIdx.x;
  if (idx >= OFF_XW) return;
  float v;
  if (idx < OFF_WX) {  // recurrent W, K in [0,256), gate-permuted per wave
    int j = idx & 7, lane = (idx >> 3) & 63, rest = idx >> 9;
    int ks = rest & 7; rest >>= 3;
    int gate = rest % 6; rest /= 6;
    int wv = rest & 7, cls = rest >> 3;
    int n = gate * 128 + wv * 16 + (lane & 15);
    int k = ks * 32 + ((lane >> 4) << 3) + j;
    v = W_enc[(cls * 768 + n) * 384 + k];
  } else if (idx < OFF_F3) {  // x-part Wx, K in [256,384)
    int f = idx - OFF_WX;
    int j = f & 7, lane = (f >> 3) & 63, rest = f >> 9;
    int ks = rest & 3; rest >>= 2;
    int wv = rest & 7; rest >>= 3;
    int gate = rest % 6, cls = rest / 6;
    int n = gate * 128 + wv * 16 + (lane & 15);
    int k = 256 + ks * 32 + ((lane >> 4) << 3) + j;
    v = W_enc[(cls * 768 + n) * 384 + k];
  } else if (idx < OFF_F4) {  // fc3
    int f = idx - OFF_F3;
    int j = f & 7, lane = (f >> 3) & 63, rest = f >> 9;
    int ks = rest & 1, wv = rest >> 1;
    int n = wv * 16 + (lane & 15), k = ks * 32 + ((lane >> 4) << 3) + j;
    v = fc3_w[n * 64 + k];
  } else {  // fc4
    int f = idx - OFF_F4;
    int j = f & 7, lane = (f >> 3) & 63, rest = f >> 9;
    int ks = rest & 3, wv = rest >> 2;
    int n = wv * 16 + (lane & 15), k = ks * 32 + ((lane >> 4) << 3) + j;
    v = fc4_w[n * 128 + k];
  }
  wsh[idx] = (hf)v;
}

// ---- kernel 2: frontend MLP + xW precompute; xWb written coalesced via LDS staging ----
__global__ __launch_bounds__(512) void prelude(
    const float* __restrict__ x, const float* __restrict__ fc3_b, const float* __restrict__ fc4_b,
    const float* __restrict__ B_enc, const hf* __restrict__ wsh, hf* __restrict__ xWb) {
  const int t = threadIdx.x, lane = t & 63, wv = t >> 6;
  const int c16 = lane & 15, quad = lane >> 4;
  const int row0 = blockIdx.x * 64, bn = row0 / 192, l0 = row0 % 192;

  __shared__ __attribute__((aligned(16))) hf xA[64 * 64];
  __shared__ __attribute__((aligned(16))) hf hbuf[64 * 128];
  __shared__ __attribute__((aligned(16))) hf xout[64 * 768];
  __shared__ float actf[64];

  {  // stage x -> fp16 swizzled LDS
    int r = t >> 3, cb = (t & 7) * 8;
    const float* xp = x + (size_t)(row0 + r) * 64 + cb;
    f32x4 a = *(const f32x4*)xp, b = *(const f32x4*)(xp + 4);
    half8 h;
    h[0] = (hf)a.x; h[1] = (hf)a.y; h[2] = (hf)a.z; h[3] = (hf)a.w;
    h[4] = (hf)b.x; h[5] = (hf)b.y; h[6] = (hf)b.z; h[7] = (hf)b.w;
    *(half8*)&xA[xidx(r, cb)] = h;
  }
  if (t < 64) {
    int l = l0 + t;
    actf[t] = ((l / 12) + (l % 12)) < 12 ? 1.f : 0.f;
  }
  __syncthreads();

  // ---- fc3: relu(x @ w3^T + b3) -> hbuf ----
  {
    float b3v = fc3_b[wv * 16 + c16];
    half8 w0 = *(const half8*)(wsh + OFF_F3 + (wv * 2 + 0) * 512 + lane * 8);
    half8 w1 = *(const half8*)(wsh + OFF_F3 + (wv * 2 + 1) * 512 + lane * 8);
    f32x4 acc[4] = {{0, 0, 0, 0}, {0, 0, 0, 0}, {0, 0, 0, 0}, {0, 0, 0, 0}};
#pragma unroll
    for (int mt = 0; mt < 4; ++mt) {
      half8 a0 = *(const half8*)&xA[xidx(mt * 16 + c16, quad * 8)];
      half8 a1 = *(const half8*)&xA[xidx(mt * 16 + c16, 32 + quad * 8)];
      acc[mt] = __builtin_amdgcn_mfma_f32_16x16x32_f16(a0, w0, acc[mt], 0, 0, 0);
      acc[mt] = __builtin_amdgcn_mfma_f32_16x16x32_f16(a1, w1, acc[mt], 0, 0, 0);
    }
#pragma unroll
    for (int mt = 0; mt < 4; ++mt)
#pragma unroll
      for (int r = 0; r < 4; ++r)
        hbuf[hidx(mt * 16 + quad * 4 + r, wv * 16 + c16)] = (hf)fmaxf(acc[mt][r] + b3v, 0.f);
  }
  __syncthreads();

  // ---- fc4: h1 @ w4^T + b4 -> hbuf (after barrier) ----
  {
    float b4v = fc4_b[wv * 16 + c16];
    half8 w4[4];
#pragma unroll
    for (int ks = 0; ks < 4; ++ks)
      w4[ks] = *(const half8*)(wsh + OFF_F4 + (wv * 4 + ks) * 512 + lane * 8);
    f32x4 acc[4] = {{0, 0, 0, 0}, {0, 0, 0, 0}, {0, 0, 0, 0}, {0, 0, 0, 0}};
#pragma unroll
    for (int mt = 0; mt < 4; ++mt)
#pragma unroll
      for (int ks = 0; ks < 4; ++ks) {
        half8 a = *(const half8*)&hbuf[hidx(mt * 16 + c16, ks * 32 + quad * 8)];
        acc[mt] = __builtin_amdgcn_mfma_f32_16x16x32_f16(a, w4[ks], acc[mt], 0, 0, 0);
      }
    __syncthreads();  // all h1 reads done before overwrite
#pragma unroll
    for (int mt = 0; mt < 4; ++mt)
#pragma unroll
      for (int r = 0; r < 4; ++r)
        hbuf[hidx(mt * 16 + quad * 4 + r, wv * 16 + c16)] = (hf)(acc[mt][r] + b4v);
  }
  __syncthreads();

  // ---- xW: hg @ Wx^T (+ masked bias); wave wv owns d in [wv*16,+16), all 6 gates ----
  half8 af[4][4];
#pragma unroll
  for (int mt = 0; mt < 4; ++mt)
#pragma unroll
    for (int ks = 0; ks < 4; ++ks)
      af[mt][ks] = *(const half8*)&hbuf[hidx(mt * 16 + c16, ks * 32 + quad * 8)];

  for (int cls = 0; cls < 2; ++cls) {
    for (int gp = 0; gp < 3; ++gp) {  // gate pair (2gp, 2gp+1), packed dword staging
      half8 wfa[4], wfb[4];
#pragma unroll
      for (int ks = 0; ks < 4; ++ks) {
        wfa[ks] = *(const half8*)(wsh + OFF_WX + ((((cls * 6 + 2 * gp) * 8 + wv) * 4) + ks) * 512 + lane * 8);
        wfb[ks] = *(const half8*)(wsh + OFF_WX + ((((cls * 6 + 2 * gp + 1) * 8 + wv) * 4) + ks) * 512 + lane * 8);
      }
      float bva = B_enc[cls * 768 + (2 * gp) * 128 + wv * 16 + c16];
      float bvb = B_enc[cls * 768 + (2 * gp + 1) * 128 + wv * 16 + c16];
#pragma unroll
      for (int mt = 0; mt < 4; ++mt) {
        f32x4 aA = {0, 0, 0, 0}, aB = {0, 0, 0, 0};
#pragma unroll
        for (int ks = 0; ks < 4; ++ks) {
          aA = __builtin_amdgcn_mfma_f32_16x16x32_f16(af[mt][ks], wfa[ks], aA, 0, 0, 0);
          aB = __builtin_amdgcn_mfma_f32_16x16x32_f16(af[mt][ks], wfb[ks], aB, 0, 0, 0);
        }
#pragma unroll
        for (int r = 0; r < 4; ++r) {
          int row = mt * 16 + quad * 4 + r;
          half2v pk = {(hf)(aA[r] + actf[row] * bva), (hf)(aB[r] + actf[row] * bvb)};
          *(half2v*)&xout[row * 768 + (wv * 16 + c16) * 6 + 2 * gp] = pk;
        }
      }
    }
    __syncthreads();  // xout complete for this class
    {  // coalesced write: 64 rows x 768 halfs = 24576 dwords
      const int* src = (const int*)xout;
      int* dst = (int*)(xWb + (((size_t)cls * 64 + bn) * 192 + l0) * 768);
#pragma unroll
      for (int i = 0; i < 12; ++i) {
        int base = (t + i * 512) * 4;
        *(int4v*)&dst[base] = *(const int4v*)&src[base];
      }
    }
    __syncthreads();  // writes done before xout reuse
  }
}

// ---- kernel 3: recurrence; gates stay in MFMA registers; A ping-pong; 1 barrier/step ----
__global__ __launch_bounds__(512) __attribute__((amdgpu_waves_per_eu(2, 2))) void witran(
    const hf* __restrict__ wsh, const float* __restrict__ fc1_w, const float* __restrict__ fc1_b,
    const float* __restrict__ fc2_w, const float* __restrict__ fc2_b,
    const hf* __restrict__ xWb, float* __restrict__ out) {
  const int cls = blockIdx.x & 1, bn = blockIdx.x >> 1;
  const int t = threadIdx.x, lane = t & 63, wv = t >> 6;
  const int c16 = lane & 15, quad = lane >> 4;
  const int d = wv * 16 + c16;  // this lane's dim

  __shared__ __attribute__((aligned(16))) hf A[2][16 * 256];
  __shared__ float red[128];

  for (int i = t; i < 4096; i += 512) ((int*)A)[i] = 0;

  // 48 register(AGPR)-resident W fragments: wave wv -> all 6 gates of d-range
  half8 w[6][8];
#pragma unroll
  for (int g = 0; g < 6; ++g)
#pragma unroll
    for (int ks = 0; ks < 8; ++ks)
      w[g][ks] = *(const half8*)(wsh + ((((cls * 8 + wv) * 6 + g) * 8) + ks) * 512 + lane * 8);

  const hf* xg = xWb + ((size_t)cls * 64 + bn) * 192 * 768;

  // xv: per slice r (c = quad*4+r), 6 gate inputs = 3 dwords at xg[cell*768 + d*6]
  int xv[4][3], xvn[4][3];
#pragma unroll
  for (int r = 0; r < 4; ++r) {
    int c = quad * 4 + r;
    int rr = 0 - c;
    if (c < 12 && rr >= 0 && rr < 16) {
      const int* p = (const int*)(xg + (size_t)(rr * 12 + c) * 768 + d * 6);
      xv[r][0] = p[0]; xv[r][1] = p[1]; xv[r][2] = p[2];
    } else {
      xv[r][0] = 0; xv[r][1] = 0; xv[r][2] = 0;
    }
  }
  __syncthreads();  // A zero-init visible

  for (int s = 0; s < Steps; ++s) {
    const hf* Ac = A[s & 1];
    hf* An = A[(s + 1) & 1];

    // ---- prefetch next step's x-gates (full-step slack) ----
#pragma unroll
    for (int r = 0; r < 4; ++r) {
      int c = quad * 4 + r;
      int rr = (s + 1) - c;
      if (c < 12 && rr >= 0 && rr < 16) {
        const int* p = (const int*)(xg + (size_t)(rr * 12 + c) * 768 + d * 6);
        xvn[r][0] = p[0]; xvn[r][1] = p[1]; xvn[r][2] = p[2];
      } else {
        xvn[r][0] = 0; xvn[r][1] = 0; xvn[r][2] = 0;
      }
    }

    // ---- GEMM: A(LDS) x W(regs); acc[g][r] = gate g of (slice quad*4+r, dim d) ----
    f32x4 acc[6] = {{0, 0, 0, 0}, {0, 0, 0, 0}, {0, 0, 0, 0},
                    {0, 0, 0, 0}, {0, 0, 0, 0}, {0, 0, 0, 0}};
#pragma unroll
    for (int ks = 0; ks < 8; ++ks) {
      half8 a = *(const half8*)&Ac[aidx(c16, ks * 32 + quad * 8)];
#pragma unroll
      for (int g = 0; g < 6; ++g)
        acc[g] = __builtin_amdgcn_mfma_f32_16x16x32_f16(a, w[g][ks], acc[g], 0, 0, 0);
    }

    // ---- in-register gated update; write new h into A_next ----
    if (quad < 3) {
#pragma unroll
      for (int r = 0; r < 4; ++r) {
        int c = quad * 4 + r;
        float hro = (float)Ac[aidx(c, d)];
        float hco = (float)Ac[aidx(c, 128 + d)];
        half2v x01 = __builtin_bit_cast(half2v, xv[r][0]);
        half2v x23 = __builtin_bit_cast(half2v, xv[r][1]);
        half2v x45 = __builtin_bit_cast(half2v, xv[r][2]);
        float ur = sigmoidf_(acc[0][r] + (float)x01[0]);
        float orr = sigmoidf_(acc[1][r] + (float)x01[1]);
        float uc = sigmoidf_(acc[2][r] + (float)x23[0]);
        float oc = sigmoidf_(acc[3][r] + (float)x23[1]);
        float ir = tanh_(acc[4][r] + (float)x45[0]);
        float ic = tanh_(acc[5][r] + (float)x45[1]);
        float hr = tanh_((1.f - ur) * hro + ur * ir) * orr;
        float hc = tanh_((1.f - uc) * hco + uc * ic) * oc;
        An[aidx(c, d)] = (hf)hr;
        int c2 = (c == 11) ? 0 : c + 1;  // roll: new h_col[c] feeds slice c+1
        An[aidx(c2, 128 + d)] = (hf)hc;
      }
    }
    __syncthreads();  // A_next complete for next step

#pragma unroll
    for (int r = 0; r < 4; ++r) {
      xv[r][0] = xvn[r][0]; xv[r][1] = xvn[r][1]; xv[r][2] = xvn[r][2];
    }
  }

  // ---- epilogue: final state in A[Steps&1] = A[1] ----
  if (t < 128) {
    float hr = (float)A[1][aidx(11, t)];
    float hc = (float)A[1][aidx(0, 128 + t)];
    red[t] = 0.5f * (hc * fc1_w[cls * 128 + t] + hr * fc2_w[cls * 128 + t]);
  }
  __syncthreads();
  if (t == 0) {
    float sum = 0.f;
    for (int i = 0; i < 128; ++i) sum += red[i];
    out[bn * 2 + cls] = sum + 0.5f * (fc1_b[cls] + fc2_b[cls]);
  }
}

extern "C" void kernel_launch(void* const* d_in, const int* in_sizes, int n_in,
                              void* d_out, int out_size, void* d_ws, size_t ws_size,
                              hipStream_t stream) {
  const float* x = (const float*)d_in[0];
  // d_in[1] = pad_mask: unused by the reference
  const float* fc3_w = (const float*)d_in[2];
  const float* fc3_b = (const float*)d_in[3];
  const float* fc4_w = (const float*)d_in[4];
  const float* fc4_b = (const float*)d_in[5];
  const float* W_enc = (const float*)d_in[6];
  const float* B_enc = (const float*)d_in[7];
  const float* fc1_w = (const float*)d_in[8];
  const float* fc1_b = (const float*)d_in[9];
  const float* fc2_w = (const float*)d_in[10];
  const float* fc2_b = (const float*)d_in[11];
  float* out = (float*)d_out;

  hf* wsh = (hf*)d_ws;        // frag tables 1,228,800 B
  hf* xWb = wsh + OFF_XW;     // 37,748,736 B ; total 38,977,536 B

  prep<<<dim3(1200), dim3(512), 0, stream>>>(fc3_w, fc4_w, W_enc, wsh);
  prelude<<<dim3(192), dim3(512), 0, stream>>>(x, fc3_b, fc4_b, B_enc, wsh, xWb);
  witran<<<dim3(128), dim3(512), 0, stream>>>(wsh, fc1_w, fc1_b, fc2_w, fc2_b, xWb, out);
}